// Round 4
// baseline (334.819 us; speedup 1.0000x reference)
//
#include <hip/hip_runtime.h>
#include <hip/hip_bf16.h>

#define ACT 14
#define CC 128
#define HH 256
#define EPB 182                 // edges per batch (14*13)
#define NB 2048
#define M2 (NB*EPB)             // 372736 edge-rows
#define NODES (NB*ACT)          // 28672
#define LP_CONST (-182.0f * 0.91893853320467274f)   // -E*0.5*ln(2pi)

typedef short s16x8 __attribute__((ext_vector_type(8)));
typedef float f32x4 __attribute__((ext_vector_type(4)));

__device__ __forceinline__ short f2bf(float f) {
    unsigned u = __float_as_uint(f);
    unsigned r = (u + 0x7fffu + ((u >> 16) & 1u)) >> 16;   // RNE
    return (short)r;
}
__device__ __forceinline__ float leaky(float x) { return fmaxf(x, 0.01f * x); }
__device__ __forceinline__ float softplusf(float x) { return x > 15.f ? x : log1pf(expf(x)); }

union bf2u { __hip_bfloat162 h; int i; short s[2]; };
__device__ __forceinline__ int pk_bf16(float a, float b) {
    bf2u u; u.h = __float22bfloat162_rn(make_float2(a, b));
    return u.i;
}

// ---------------------------------------------------------------------------
// Kernel 0 (prep): weight transposes / bf16 pre-conversions (one-time, tiny)
//   W2bf[n*256+k] = bf16(lin2_w[n][k])
//   W1bf[n*128+k] = bf16(W1L[n][k]) n<256, bf16(W1R[n-256][k]) n>=256
//   cwT [k*128+j] = conv_w[j][k]
//   w1sT[k*256+h] = lin1_w[h][k] + lin1_w[h][128+k]
// ---------------------------------------------------------------------------
__global__ __launch_bounds__(256) void prep_kernel(
    const float* __restrict__ conv_w, const float* __restrict__ lin1_w,
    const float* __restrict__ lin2_w, short* __restrict__ W2bf,
    short* __restrict__ W1bf, float* __restrict__ cwT, float* __restrict__ w1sT)
{
    int i = blockIdx.x * 256 + threadIdx.x;      // grid = 256 blocks -> 65536
    W2bf[i] = f2bf(lin2_w[i]);
    {
        int n = i >> 7, k = i & 127;
        float v = (n < 256) ? lin1_w[n * 256 + k] : lin1_w[(n - 256) * 256 + 128 + k];
        W1bf[i] = f2bf(v);
    }
    if (i < 16384) {
        int k = i >> 7, j = i & 127;
        cwT[i] = conv_w[j * 128 + k];
    }
    if (i < 32768) {
        int k = i >> 8, h = i & 255;
        w1sT[i] = lin1_w[h * 256 + k] + lin1_w[h * 256 + 128 + k];
    }
}

// ---------------------------------------------------------------------------
// Kernel 1: per-batch wvec[b] = w1sT^T @ relu(cwT^T @ (ssum/14) + conv_b) + lin1_b
// ---------------------------------------------------------------------------
#define BPB 4
__global__ __launch_bounds__(256) void gw_kernel(
    const float* __restrict__ state, const float* __restrict__ cwT,
    const float* __restrict__ conv_b, const float* __restrict__ w1sT,
    const float* __restrict__ lin1_b, float* __restrict__ wvec)
{
    __shared__ float ssum[BPB][CC];
    __shared__ float g[BPB][CC];
    const int t = threadIdx.x;
    const int b0 = blockIdx.x * BPB;

    #pragma unroll
    for (int it = 0; it < 2; ++it) {
        int idx = t + it * 256;
        int bb = idx >> 7, c = idx & 127;
        const float* sp = state + (size_t)(b0 + bb) * (ACT * CC) + c;
        float s = 0.f;
        #pragma unroll
        for (int i = 0; i < ACT; ++i) s += sp[i * CC];
        ssum[bb][c] = s * (1.f / 14.f);
    }
    __syncthreads();

    {
        int j = t & 127, half = t >> 7;
        float a0 = 0.f, a1 = 0.f;
        #pragma unroll 4
        for (int k = 0; k < CC; ++k) {
            float wv = cwT[k * CC + j];
            a0 += wv * ssum[half * 2 + 0][k];
            a1 += wv * ssum[half * 2 + 1][k];
        }
        float cb = conv_b[j];
        g[half * 2 + 0][j] = fmaxf(a0 + cb, 0.f);
        g[half * 2 + 1][j] = fmaxf(a1 + cb, 0.f);
    }
    __syncthreads();

    {
        float a[BPB] = {0.f, 0.f, 0.f, 0.f};
        #pragma unroll 4
        for (int k = 0; k < CC; ++k) {
            float wv = w1sT[k * HH + t];
            #pragma unroll
            for (int b = 0; b < BPB; ++b) a[b] += wv * g[b][k];
        }
        float lb = lin1_b[t];
        #pragma unroll
        for (int b = 0; b < BPB; ++b)
            wvec[(size_t)(b0 + b) * HH + t] = a[b] + lb;
    }
}

// ---------------------------------------------------------------------------
// Kernel 2 (mega): one block per batch. 1024 threads = 16 waves (4wy x 4wx).
//  Phase A: stage state(14x128) as bf16 A1; load wvec[b] -> wvL.
//  Phase B: in-block node GEMM -> nodeL[n][0:256]=u+w, [256:512]=v (bf16).
//  Phase C: K-loop (8 chunks): cooperative H1=leaky(u'+v') build into
//           double-buffered h1L (each element computed ONCE), frag reads
//           via ds_read_b128; B from L2-hot W2bf with 1-chunk prefetch.
//  Phase D: fused epilogue: h2=leaky(.+b2), mu/sig head dots, softplus,
//           action + block-local log_prob.
// ---------------------------------------------------------------------------
__global__ __launch_bounds__(1024, 4) void actor_kernel(
    const float* __restrict__ state, const short* __restrict__ W1bf,
    const float* __restrict__ wvec, const short* __restrict__ W2bf,
    const float* __restrict__ lin2_b,
    const float* __restrict__ mu_w, const float* __restrict__ mu_b,
    const float* __restrict__ sig_w, const float* __restrict__ sig_b,
    const float* __restrict__ noise, const int* __restrict__ edges,
    float* __restrict__ out)
{
    __shared__ short A1[4 * 16 * 40];        // state bf16, per-chunk [row][k] stride 40
    __shared__ float wvL[256];
    __shared__ short nodeL[14 * 520];        // u'(+w) | v' bf16, stride 520
    __shared__ short h1L[2][192 * 40];       // H1 chunk double buffer
    __shared__ float mu_acc[192], sg_acc[192];
    __shared__ float lp_acc;

    const int t = threadIdx.x;
    const int b = blockIdx.x;
    const int lane = t & 63, ln = lane & 15, q = lane >> 4;
    const int wave = t >> 6;                  // 0..15
    const int wy = wave >> 2, wx = wave & 3;

    // ---- phase A ----
    if (t < 512) {
        int row = t >> 5, c4 = t & 31;                 // 16 rows x 32 f32x4
        int kk = c4 >> 3, k8 = (c4 & 7) * 4;           // shorts offset within chunk
        int* dst = (int*)&A1[kk * 640 + row * 40 + k8];
        if (row < ACT) {
            f32x4 x = *(const f32x4*)(state + (size_t)(b * ACT + row) * CC + c4 * 4);
            dst[0] = pk_bf16(x[0], x[1]);
            dst[1] = pk_bf16(x[2], x[3]);
        } else {
            dst[0] = 0; dst[1] = 0;
        }
    } else if (t < 768) {
        wvL[t - 512] = wvec[(size_t)b * HH + (t - 512)];
    }
    if (t < 192) { mu_acc[t] = 0.f; sg_acc[t] = 0.f; }
    if (t == 0) lp_acc = 0.f;
    __syncthreads();

    // ---- phase B: node GEMM (16 waves x 2 col-tiles of 16 = 512 cols) ----
    #pragma unroll
    for (int ti = 0; ti < 2; ++ti) {
        int nt = wave * 2 + ti;                         // 0..31
        const short* bp1 = W1bf + (size_t)(nt * 16 + ln) * CC + q * 8;
        f32x4 acc4 = {0.f, 0.f, 0.f, 0.f};
        #pragma unroll
        for (int kk = 0; kk < 4; ++kk) {
            s16x8 a8 = *(s16x8*)&A1[kk * 640 + ln * 40 + q * 8];
            s16x8 b8 = *(const s16x8*)(bp1 + kk * 32);
            acc4 = __builtin_amdgcn_mfma_f32_16x16x32_bf16(a8, b8, acc4, 0, 0, 0);
        }
        int col = nt * 16 + ln;
        float wadd = (col < 256) ? wvL[col] : 0.f;
        #pragma unroll
        for (int rg = 0; rg < 4; ++rg) {
            int node = q * 4 + rg;
            if (node < ACT)
                nodeL[node * 520 + col] = f2bf(acc4[rg] + wadd);
        }
    }

    // per-thread H1 build row (fixed): 728 active threads x 8 shorts
    const int r_b = t >> 2;                   // 0..255; active < 192
    const int k8b = (t & 3) * 8;
    int ubo = k8b, vbo = 256 + k8b;
    if (r_b < EPB) {
        int2 p = ((const int2*)edges)[r_b];
        ubo += p.x * 520;
        vbo += p.y * 520;
    }
    const short* bp2 = W2bf + (size_t)(wx * 64 + ln) * HH + q * 8;

    __syncthreads();   // nodeL ready

    auto build = [&](int kk, int buf) {
        if (r_b < 192) {
            int o[4] = {0, 0, 0, 0};
            if (r_b < EPB) {
                s16x8 u8 = *(const s16x8*)&nodeL[ubo + kk * 32];
                s16x8 v8 = *(const s16x8*)&nodeL[vbo + kk * 32];
                const int* ui = (const int*)&u8;
                const int* vi = (const int*)&v8;
                #pragma unroll
                for (int j = 0; j < 4; ++j) {
                    int uu = ui[j], vv = vi[j];
                    float s0 = __uint_as_float(((unsigned)uu) << 16) +
                               __uint_as_float(((unsigned)vv) << 16);
                    float s1 = __uint_as_float((unsigned)uu & 0xffff0000u) +
                               __uint_as_float((unsigned)vv & 0xffff0000u);
                    o[j] = pk_bf16(leaky(s0), leaky(s1));
                }
            }
            *(s16x8*)&h1L[buf][r_b * 40 + k8b] = *(s16x8*)o;
        }
    };

    f32x4 zero = {0.f, 0.f, 0.f, 0.f};
    f32x4 acc[3][4];
    #pragma unroll
    for (int i = 0; i < 3; ++i)
        #pragma unroll
        for (int j = 0; j < 4; ++j) acc[i][j] = zero;

    build(0, 0);
    s16x8 bcur[4], bnxt[4];
    #pragma unroll
    for (int fc = 0; fc < 4; ++fc)
        bcur[fc] = *(const s16x8*)(bp2 + fc * 16 * HH);

    for (int kk = 0; kk < 8; ++kk) {
        int cur = kk & 1;
        if (kk < 7) {
            #pragma unroll
            for (int fc = 0; fc < 4; ++fc)
                bnxt[fc] = *(const s16x8*)(bp2 + fc * 16 * HH + (kk + 1) * 32);
        }
        __syncthreads();                       // h1L[cur] built; prev reads done
        s16x8 af[3];
        #pragma unroll
        for (int fr = 0; fr < 3; ++fr)
            af[fr] = *(s16x8*)&h1L[cur][(wy * 48 + fr * 16 + ln) * 40 + q * 8];
        if (kk < 7) build(kk + 1, cur ^ 1);
        #pragma unroll
        for (int fr = 0; fr < 3; ++fr)
            #pragma unroll
            for (int fc = 0; fc < 4; ++fc)
                acc[fr][fc] = __builtin_amdgcn_mfma_f32_16x16x32_bf16(af[fr], bcur[fc], acc[fr][fc], 0, 0, 0);
        #pragma unroll
        for (int fc = 0; fc < 4; ++fc) bcur[fc] = bnxt[fc];
    }

    // ---- phase D: fused epilogue ----
    float pmu[3][4], psg[3][4];
    #pragma unroll
    for (int fr = 0; fr < 3; ++fr)
        #pragma unroll
        for (int rg = 0; rg < 4; ++rg) { pmu[fr][rg] = 0.f; psg[fr][rg] = 0.f; }

    #pragma unroll
    for (int fc = 0; fc < 4; ++fc) {
        int col = wx * 64 + fc * 16 + ln;
        float bb = lin2_b[col], mw = mu_w[col], sw = sig_w[col];
        #pragma unroll
        for (int fr = 0; fr < 3; ++fr)
            #pragma unroll
            for (int rg = 0; rg < 4; ++rg) {
                float h2 = leaky(acc[fr][fc][rg] + bb);
                pmu[fr][rg] += mw * h2;
                psg[fr][rg] += sw * h2;
            }
    }
    #pragma unroll
    for (int fr = 0; fr < 3; ++fr)
        #pragma unroll
        for (int rg = 0; rg < 4; ++rg) {
            float a = pmu[fr][rg], s2 = psg[fr][rg];
            #pragma unroll
            for (int off = 1; off < 16; off <<= 1) {
                a  += __shfl_xor(a, off);
                s2 += __shfl_xor(s2, off);
            }
            if (ln == 0) {
                int row = wy * 48 + fr * 16 + q * 4 + rg;
                atomicAdd(&mu_acc[row], a);
                atomicAdd(&sg_acc[row], s2);
            }
        }
    __syncthreads();

    if (t < EPB) {
        float mu = softplusf(mu_acc[t] + mu_b[0]);
        float sd = softplusf(sg_acc[t] + sig_b[0]);
        float z = noise[(size_t)b * EPB + t];
        out[(size_t)b * EPB + t] = mu + sd * z;
        atomicAdd(&lp_acc, -0.5f * z * z - logf(sd));
    }
    __syncthreads();
    if (t == 0) out[M2 + b] = lp_acc + LP_CONST;
}

// ---------------------------------------------------------------------------
extern "C" void kernel_launch(void* const* d_in, const int* in_sizes, int n_in,
                              void* d_out, int out_size, void* d_ws, size_t ws_size,
                              hipStream_t stream)
{
    const float* state  = (const float*)d_in[0];
    const float* conv_w = (const float*)d_in[1];
    const float* conv_b = (const float*)d_in[2];
    const float* lin1_w = (const float*)d_in[3];
    const float* lin1_b = (const float*)d_in[4];
    const float* lin2_w = (const float*)d_in[5];
    const float* lin2_b = (const float*)d_in[6];
    const float* mu_w   = (const float*)d_in[7];
    const float* mu_b   = (const float*)d_in[8];
    const float* sig_w  = (const float*)d_in[9];
    const float* sig_b  = (const float*)d_in[10];
    const float* noise  = (const float*)d_in[11];
    const int*   edges  = (const int*)d_in[13];
    float* out = (float*)d_out;

    char* ws = (char*)d_ws;
    float* wvec = (float*)ws;   ws += (size_t)NB * HH * 4;      // 2 MB
    short* W2bf = (short*)ws;   ws += 65536 * 2;
    short* W1bf = (short*)ws;   ws += 65536 * 2;
    float* cwT  = (float*)ws;   ws += 16384 * 4;
    float* w1sT = (float*)ws;   ws += 32768 * 4;

    prep_kernel<<<256, 256, 0, stream>>>(conv_w, lin1_w, lin2_w, W2bf, W1bf, cwT, w1sT);
    gw_kernel<<<NB / BPB, 256, 0, stream>>>(state, cwT, conv_b, w1sT, lin1_b, wvec);
    actor_kernel<<<NB, 1024, 0, stream>>>(state, W1bf, wvec, W2bf, lin2_b,
                                          mu_w, mu_b, sig_w, sig_b,
                                          noise, edges, out);
}

// Round 6
// 255.686 us; speedup vs baseline: 1.3095x; 1.3095x over previous
//
#include <hip/hip_runtime.h>
#include <hip/hip_bf16.h>

#define ACT 14
#define CC 128
#define HH 256
#define EPB 182                 // edges per batch (14*13)
#define NB 2048
#define M2 (NB*EPB)             // 372736 edge-rows
#define NS 520                  // nodeL stride in shorts (1040B = 65*16, b128-aligned)
#define LP_CONST (-182.0f * 0.91893853320467274f)   // -E*0.5*ln(2pi)

typedef short s16x8 __attribute__((ext_vector_type(8)));
typedef float f32x4 __attribute__((ext_vector_type(4)));
typedef float f32x16 __attribute__((ext_vector_type(16)));

__device__ __forceinline__ short f2bf(float f) {
    unsigned u = __float_as_uint(f);
    unsigned r = (u + 0x7fffu + ((u >> 16) & 1u)) >> 16;   // RNE
    return (short)r;
}
__device__ __forceinline__ float bflo(int m) { return __uint_as_float(((unsigned)m) << 16); }
__device__ __forceinline__ float bfhi(int m) { return __uint_as_float((unsigned)m & 0xffff0000u); }
__device__ __forceinline__ float leaky(float x) { return fmaxf(x, 0.01f * x); }
__device__ __forceinline__ float softplusf(float x) { return x > 15.f ? x : log1pf(expf(x)); }

union bf2u { __hip_bfloat162 h; int i; };
__device__ __forceinline__ int pk_bf16(float a, float b) {
    bf2u u; u.h = __float22bfloat162_rn(make_float2(a, b));
    return u.i;
}

// ---------------------------------------------------------------------------
// prep: one-time weight conversions (256 blocks x 256)
//   W2bf [n*256+k] = bf16(lin2_w[n][k])
//   W1bf [n*128+k] = bf16(W1L[n][k]) n<256 ; bf16(W1R[n-256][k]) n>=256
//   cwbf [j*128+k] = bf16(conv_w[j][k])          (row-major, no transpose)
//   w1sbf[h*128+k] = bf16(lin1_w[h][k]+lin1_w[h][128+k])
//   msbf [n]       = pack(bf16(mu_w[n]), bf16(sig_w[n]))
//   b2p  [p]       = pack(bf16(lin2_b[2p]), bf16(lin2_b[2p+1]))
// ---------------------------------------------------------------------------
__global__ __launch_bounds__(256) void prep_kernel(
    const float* __restrict__ conv_w, const float* __restrict__ lin1_w,
    const float* __restrict__ lin2_w, const float* __restrict__ mu_w,
    const float* __restrict__ sig_w, const float* __restrict__ lin2_b,
    short* __restrict__ W2bf, short* __restrict__ W1bf,
    short* __restrict__ cwbf, short* __restrict__ w1sbf,
    int* __restrict__ msbf, int* __restrict__ b2p)
{
    int i = blockIdx.x * 256 + threadIdx.x;
    W2bf[i] = f2bf(lin2_w[i]);
    {
        int n = i >> 7, k = i & 127;
        float v = (n < 256) ? lin1_w[n * 256 + k] : lin1_w[(n - 256) * 256 + 128 + k];
        W1bf[i] = f2bf(v);
    }
    if (i < 16384) cwbf[i] = f2bf(conv_w[i]);
    if (i < 32768) {
        int h = i >> 7, k = i & 127;
        w1sbf[i] = f2bf(lin1_w[h * 256 + k] + lin1_w[h * 256 + 128 + k]);
    }
    if (i < 256) msbf[i] = pk_bf16(mu_w[i], sig_w[i]);
    if (i < 128) b2p[i] = pk_bf16(lin2_b[2 * i], lin2_b[2 * i + 1]);
}

// ---------------------------------------------------------------------------
// gw_mfma: 256 blocks x 8 batches. Two chained 16x16x32 MFMA GEMMs:
//   g = relu(ssum/14 @ conv_w^T + conv_b) ; wvec = g @ w1s^T + lin1_b
// ---------------------------------------------------------------------------
__global__ __launch_bounds__(256) void gw_mfma(
    const float* __restrict__ state, const short* __restrict__ cwbf,
    const float* __restrict__ conv_b, const short* __restrict__ w1sbf,
    const float* __restrict__ lin1_b, float* __restrict__ wvec)
{
    __shared__ short ssbf[4][16 * 40];
    __shared__ short gbf[4][16 * 40];
    const int t = threadIdx.x;
    const int b0 = blockIdx.x * 8;
    const int lane = t & 63, ln = lane & 15, q = lane >> 4, w = t >> 6;

    #pragma unroll
    for (int j = 0; j < 8; ++j) {               // ssum (rows 8..15 zero-pad)
        int idx = j * 256 + t;
        int bb = idx >> 7, c = idx & 127;
        float s = 0.f;
        if (bb < 8) {
            const float* sp = state + ((size_t)(b0 + bb) * ACT) * CC + c;
            #pragma unroll
            for (int r = 0; r < ACT; ++r) s += sp[r * CC];
            s *= (1.f / 14.f);
        }
        ssbf[c >> 5][bb * 40 + (c & 31)] = f2bf(s);
    }
    __syncthreads();

    f32x4 zero4 = {0.f, 0.f, 0.f, 0.f};
    f32x4 g1[2];
    g1[0] = zero4; g1[1] = zero4;
    #pragma unroll
    for (int c = 0; c < 4; ++c) {
        s16x8 a8 = *(const s16x8*)&ssbf[c][ln * 40 + q * 8];
        #pragma unroll
        for (int i = 0; i < 2; ++i) {
            int ct = w * 2 + i;
            s16x8 b8 = *(const s16x8*)&cwbf[(ct * 16 + ln) * CC + c * 32 + q * 8];
            g1[i] = __builtin_amdgcn_mfma_f32_16x16x32_bf16(a8, b8, g1[i], 0, 0, 0);
        }
    }
    #pragma unroll
    for (int i = 0; i < 2; ++i) {
        int col = (w * 2 + i) * 16 + ln;
        float cb = conv_b[col];
        #pragma unroll
        for (int rg = 0; rg < 4; ++rg)
            gbf[col >> 5][(q * 4 + rg) * 40 + (col & 31)] = f2bf(fmaxf(g1[i][rg] + cb, 0.f));
    }
    __syncthreads();

    f32x4 g2[4];
    g2[0] = zero4; g2[1] = zero4; g2[2] = zero4; g2[3] = zero4;
    #pragma unroll
    for (int c = 0; c < 4; ++c) {
        s16x8 a8 = *(const s16x8*)&gbf[c][ln * 40 + q * 8];
        #pragma unroll
        for (int i = 0; i < 4; ++i) {
            int ct = w * 4 + i;
            s16x8 b8 = *(const s16x8*)&w1sbf[(ct * 16 + ln) * CC + c * 32 + q * 8];
            g2[i] = __builtin_amdgcn_mfma_f32_16x16x32_bf16(a8, b8, g2[i], 0, 0, 0);
        }
    }
    #pragma unroll
    for (int i = 0; i < 4; ++i) {
        int col = (w * 4 + i) * 16 + ln;
        float lb = lin1_b[col];
        #pragma unroll
        for (int rg = 0; rg < 4; ++rg) {
            int row = q * 4 + rg;
            if (row < 8) wvec[(size_t)(b0 + row) * HH + col] = g2[i][rg] + lb;
        }
    }
}

// ---------------------------------------------------------------------------
// actor: one block per batch, 256 threads = 4 waves = 4 n-strips of 64.
//  A: stage state bf16 + load wvec.  B: node GEMM -> nodeL (u+w | v).
//  C: 6 M-tiles of 32 edges; cooperative H1 build into frag-order LDS
//     (double-buffered, 1 barrier/tile); W2 K=256 entirely in VGPRs;
//     32x32x16 MFMA; in-lane mu/sig reduction (edge on lane&31).
// ---------------------------------------------------------------------------
__global__ __launch_bounds__(256, 2) void actor_kernel(
    const float* __restrict__ state, const short* __restrict__ W1bf,
    const float* __restrict__ wvec, const short* __restrict__ W2bf,
    const int* __restrict__ b2p, const int* __restrict__ msbf,
    const float* __restrict__ mu_b, const float* __restrict__ sig_b,
    const float* __restrict__ noise, const int* __restrict__ edges,
    float* __restrict__ out)
{
    __shared__ short stateL[4 * 16 * 40];    // per-chunk [row][k], stride 40
    __shared__ short nodeL[ACT * NS];        // u'(+w) | v'
    __shared__ short h1L[2][16 * 512];       // frag-order: chunk*512 + lane*8
    __shared__ float wvL[256];
    __shared__ float mu_acc[192], sg_acc[192];
    __shared__ float lp_acc;

    const int t = threadIdx.x, b = blockIdx.x;
    const int lane = t & 63, ln = lane & 15, q = lane >> 4, w = t >> 6;
    const int l32 = lane & 31, hf = lane >> 5;

    // ---- phase A ----
    #pragma unroll
    for (int it = 0; it < 2; ++it) {
        int idx = it * 256 + t, row = idx >> 5, c4 = idx & 31;
        int kk = c4 >> 3, k8 = (c4 & 7) * 4;
        int* dst = (int*)&stateL[kk * 640 + row * 40 + k8];
        if (row < ACT) {
            f32x4 x = *(const f32x4*)(state + ((size_t)b * ACT + row) * CC + c4 * 4);
            dst[0] = pk_bf16(x[0], x[1]); dst[1] = pk_bf16(x[2], x[3]);
        } else { dst[0] = 0; dst[1] = 0; }
    }
    wvL[t] = wvec[(size_t)b * HH + t];
    if (t < 192) { mu_acc[t] = 0.f; sg_acc[t] = 0.f; }
    if (t == 0) lp_acc = 0.f;
    __syncthreads();

    // ---- phase B: node GEMM (u = W1L@x + w, v = W1R@x) ----
    f32x4 zero4 = {0.f, 0.f, 0.f, 0.f};
    f32x4 nacc[8];
    #pragma unroll
    for (int i = 0; i < 8; ++i) nacc[i] = zero4;
    #pragma unroll
    for (int c = 0; c < 4; ++c) {
        s16x8 a8 = *(const s16x8*)&stateL[c * 640 + ln * 40 + q * 8];
        #pragma unroll
        for (int i = 0; i < 8; ++i) {
            s16x8 b8 = *(const s16x8*)&W1bf[(size_t)((w + 4 * i) * 16 + ln) * CC + c * 32 + q * 8];
            nacc[i] = __builtin_amdgcn_mfma_f32_16x16x32_bf16(a8, b8, nacc[i], 0, 0, 0);
        }
    }
    #pragma unroll
    for (int i = 0; i < 8; ++i) {
        int col = (w + 4 * i) * 16 + ln;
        float wadd = (col < HH) ? wvL[col] : 0.f;
        #pragma unroll
        for (int rg = 0; rg < 4; ++rg) {
            int node = q * 4 + rg;
            if (node < ACT) nodeL[node * NS + col] = f2bf(nacc[i][rg] + wadd);
        }
    }

    // ---- W2 strip (K=256) into VGPRs + epilogue tables ----
    s16x8 wa[2][16];
    #pragma unroll
    for (int s = 0; s < 2; ++s)
        #pragma unroll
        for (int c = 0; c < 16; ++c)
            wa[s][c] = *(const s16x8*)&W2bf[(size_t)(w * 64 + s * 32 + l32) * HH + c * 16 + hf * 8];
    int b2k[2][8], msk[2][16];
    #pragma unroll
    for (int s = 0; s < 2; ++s) {
        int ns = w * 64 + s * 32;
        #pragma unroll
        for (int a = 0; a < 4; ++a) {
            b2k[s][a * 2]     = b2p[(ns >> 1) + 4 * a + 2 * hf];
            b2k[s][a * 2 + 1] = b2p[(ns >> 1) + 4 * a + 2 * hf + 1];
        }
        #pragma unroll
        for (int r = 0; r < 16; ++r)
            msk[s][r] = msbf[ns + (r & 3) + 8 * (r >> 2) + 4 * hf];
    }
    __syncthreads();   // nodeL visible

    auto build = [&](int tile, int bufi) {
        int e = tile * 32 + (t & 31);
        int uo = 0, vo = 0;
        bool ok = e < EPB;
        if (ok) { int2 p = ((const int2*)edges)[e]; uo = p.x * NS; vo = p.y * NS + HH; }
        #pragma unroll
        for (int s = 0; s < 4; ++s) {
            int chunk = (t >> 6) + 4 * s;
            int koff = chunk * 16 + ((t >> 5) & 1) * 8;
            int o[4] = {0, 0, 0, 0};
            if (ok) {
                s16x8 u8 = *(const s16x8*)&nodeL[uo + koff];
                s16x8 v8 = *(const s16x8*)&nodeL[vo + koff];
                const int* ui = (const int*)&u8;
                const int* vi = (const int*)&v8;
                #pragma unroll
                for (int j = 0; j < 4; ++j) {
                    int uu = ui[j], vv = vi[j];
                    float s0 = bflo(uu) + bflo(vv);
                    float s1 = bfhi(uu) + bfhi(vv);
                    o[j] = pk_bf16(leaky(s0), leaky(s1));
                }
            }
            *(s16x8*)&h1L[bufi][chunk * 512 + (t & 63) * 8] = *(const s16x8*)o;
        }
    };

    build(0, 0);
    for (int tile = 0; tile < 6; ++tile) {
        __syncthreads();
        if (tile < 5) build(tile + 1, (tile + 1) & 1);
        const int buf = tile & 1;
        f32x16 acc0, acc1;
        #pragma unroll
        for (int r = 0; r < 16; ++r) { acc0[r] = 0.f; acc1[r] = 0.f; }
        #pragma unroll
        for (int c = 0; c < 16; ++c) {
            s16x8 b8 = *(const s16x8*)&h1L[buf][c * 512 + lane * 8];
            acc0 = __builtin_amdgcn_mfma_f32_32x32x16_bf16(wa[0][c], b8, acc0, 0, 0, 0);
            acc1 = __builtin_amdgcn_mfma_f32_32x32x16_bf16(wa[1][c], b8, acc1, 0, 0, 0);
        }
        // in-lane epilogue: lane = edge col; regs = n rows
        float pmu = 0.f, psg = 0.f;
        #pragma unroll
        for (int s = 0; s < 2; ++s)
            #pragma unroll
            for (int r = 0; r < 16; ++r) {
                float zz = (s == 0) ? acc0[r] : acc1[r];
                int bp = b2k[s][(r >> 2) * 2 + ((r & 3) >> 1)];
                float b2v = (r & 1) ? bfhi(bp) : bflo(bp);
                float h2 = leaky(zz + b2v);
                int ms = msk[s][r];
                pmu += bflo(ms) * h2;
                psg += bfhi(ms) * h2;
            }
        pmu += __shfl_xor(pmu, 32);
        psg += __shfl_xor(psg, 32);
        if (lane < 32) {
            atomicAdd(&mu_acc[tile * 32 + lane], pmu);
            atomicAdd(&sg_acc[tile * 32 + lane], psg);
        }
    }
    __syncthreads();

    if (t < EPB) {
        float mu = softplusf(mu_acc[t] + mu_b[0]);
        float sd = softplusf(sg_acc[t] + sig_b[0]);
        float z = noise[(size_t)b * EPB + t];
        out[(size_t)b * EPB + t] = mu + sd * z;
        atomicAdd(&lp_acc, -0.5f * z * z - logf(sd));
    }
    __syncthreads();
    if (t == 0) out[M2 + b] = lp_acc + LP_CONST;
}

// ---------------------------------------------------------------------------
extern "C" void kernel_launch(void* const* d_in, const int* in_sizes, int n_in,
                              void* d_out, int out_size, void* d_ws, size_t ws_size,
                              hipStream_t stream)
{
    const float* state  = (const float*)d_in[0];
    const float* conv_w = (const float*)d_in[1];
    const float* conv_b = (const float*)d_in[2];
    const float* lin1_w = (const float*)d_in[3];
    const float* lin1_b = (const float*)d_in[4];
    const float* lin2_w = (const float*)d_in[5];
    const float* lin2_b = (const float*)d_in[6];
    const float* mu_w   = (const float*)d_in[7];
    const float* mu_b   = (const float*)d_in[8];
    const float* sig_w  = (const float*)d_in[9];
    const float* sig_b  = (const float*)d_in[10];
    const float* noise  = (const float*)d_in[11];
    const int*   edges  = (const int*)d_in[13];
    float* out = (float*)d_out;

    char* ws = (char*)d_ws;
    float* wvec  = (float*)ws;  ws += (size_t)NB * HH * 4;   // 2 MB
    short* W2bf  = (short*)ws;  ws += 65536 * 2;
    short* W1bf  = (short*)ws;  ws += 65536 * 2;
    short* cwbf  = (short*)ws;  ws += 16384 * 2;
    short* w1sbf = (short*)ws;  ws += 32768 * 2;
    int*   msbf  = (int*)ws;    ws += 256 * 4;
    int*   b2p   = (int*)ws;    ws += 128 * 4;

    prep_kernel<<<256, 256, 0, stream>>>(conv_w, lin1_w, lin2_w, mu_w, sig_w, lin2_b,
                                         W2bf, W1bf, cwbf, w1sbf, msbf, b2p);
    gw_mfma<<<NB / 8, 256, 0, stream>>>(state, cwbf, conv_b, w1sbf, lin1_b, wvec);
    actor_kernel<<<NB, 256, 0, stream>>>(state, W1bf, wvec, W2bf, b2p, msbf,
                                         mu_b, sig_b, noise, edges, out);
}

// Round 7
// 237.239 us; speedup vs baseline: 1.4113x; 1.0778x over previous
//
#include <hip/hip_runtime.h>
#include <hip/hip_bf16.h>

#define ACT 14
#define CC 128
#define HH 256
#define EPB 182                 // edges per batch (14*13)
#define NB 2048
#define M2 (NB*EPB)             // 372736 edge-rows
#define NS 520                  // nodeL stride in shorts
#define LP_CONST (-182.0f * 0.91893853320467274f)   // -E*0.5*ln(2pi)

typedef short s16x8 __attribute__((ext_vector_type(8)));
typedef float f32x4 __attribute__((ext_vector_type(4)));
typedef float f32x16 __attribute__((ext_vector_type(16)));

__device__ __forceinline__ short f2bf(float f) {
    unsigned u = __float_as_uint(f);
    unsigned r = (u + 0x7fffu + ((u >> 16) & 1u)) >> 16;   // RNE
    return (short)r;
}
__device__ __forceinline__ float b2f(short s) {
    return __uint_as_float(((unsigned)(unsigned short)s) << 16);
}
__device__ __forceinline__ float bflo(int m) { return __uint_as_float(((unsigned)m) << 16); }
__device__ __forceinline__ float bfhi(int m) { return __uint_as_float((unsigned)m & 0xffff0000u); }
__device__ __forceinline__ float leaky(float x) { return fmaxf(x, 0.01f * x); }
__device__ __forceinline__ float softplusf(float x) { return x > 15.f ? x : log1pf(expf(x)); }

union bf2u { __hip_bfloat162 h; int i; };
__device__ __forceinline__ int pk_bf16(float a, float b) {
    bf2u u; u.h = __float22bfloat162_rn(make_float2(a, b));
    return u.i;
}

// ---------------------------------------------------------------------------
// prep: one-time weight conversions (256 blocks x 256)
//   W2bf  [n*256+k] = bf16(lin2_w[n][k])
//   W1bf  [n*128+k] = bf16(W1L[n][k]) n<256 ; bf16(W1R[n-256][k]) n>=256
//   cwTbf [k*128+j] = bf16(conv_w[j][k])        (transposed: coalesced j)
//   w1sTbf[k*256+h] = bf16(lin1_w[h][k]+lin1_w[h][128+k])  (transposed)
// ---------------------------------------------------------------------------
__global__ __launch_bounds__(256) void prep_kernel(
    const float* __restrict__ conv_w, const float* __restrict__ lin1_w,
    const float* __restrict__ lin2_w,
    short* __restrict__ W2bf, short* __restrict__ W1bf,
    short* __restrict__ cwTbf, short* __restrict__ w1sTbf)
{
    int i = blockIdx.x * 256 + threadIdx.x;
    W2bf[i] = f2bf(lin2_w[i]);
    {
        int n = i >> 7, k = i & 127;
        float v = (n < 256) ? lin1_w[n * 256 + k] : lin1_w[(n - 256) * 256 + 128 + k];
        W1bf[i] = f2bf(v);
    }
    if (i < 16384) {
        int k = i >> 7, j = i & 127;
        cwTbf[i] = f2bf(conv_w[j * 128 + k]);
    }
    if (i < 32768) {
        int k = i >> 8, h = i & 255;
        w1sTbf[i] = f2bf(lin1_w[h * 256 + k] + lin1_w[h * 256 + 128 + k]);
    }
}

// ---------------------------------------------------------------------------
// actor: one block per batch, 512 threads = 8 waves; each wave owns a 32-row
// n-strip of W2 (wa[16] = 64 VGPRs, K=256 fully in regs).
//  A : stage state bf16; LDS tables (b2/mu/sig); ssum (fused GCN).
//  A2: g = relu(cwT^T ssum + cb); w = w1sT^T g + l1b  (VALU, in-block)
//  B : node GEMM -> nodeL (u+w | v) via MFMA 16x16x32.
//  C : 6 edge-tiles of 32; cooperative H1 build (each elem once) into
//      frag-order LDS, double-buffered, 1 barrier/tile; 32x32x16 MFMA;
//      in-lane mu/sig epilogue (edge on lane&31, n in regs).
// ---------------------------------------------------------------------------
__global__ __launch_bounds__(512, 4) void actor_kernel(
    const float* __restrict__ state, const short* __restrict__ W1bf,
    const short* __restrict__ W2bf,
    const short* __restrict__ cwTbf, const float* __restrict__ conv_b,
    const short* __restrict__ w1sTbf, const float* __restrict__ lin1_b,
    const float* __restrict__ lin2_b, const float* __restrict__ mu_w,
    const float* __restrict__ mu_b, const float* __restrict__ sig_w,
    const float* __restrict__ sig_b, const float* __restrict__ noise,
    const int* __restrict__ edges, float* __restrict__ out)
{
    __shared__ short stateL[4 * 16 * 40];    // 5120 B
    __shared__ short h1L[2][16 * 512];       // 32768 B
    __shared__ short nodeL[ACT * NS];        // 14560 B
    __shared__ float ssumL[128], gL[128], wL[256];
    __shared__ float b2L[256], muL[256], sgL[256];
    __shared__ float mu_acc[192], sg_acc[192];
    __shared__ float lp_acc;

    const int t = threadIdx.x, b = blockIdx.x;
    const int lane = t & 63, ln = lane & 15, q = lane >> 4;
    const int w = t >> 6;                     // wave 0..7
    const int l32 = lane & 31, hf = lane >> 5;

    // ---- phase A ----
    {
        int row = t >> 5, c4 = t & 31;        // 16 rows x 32 f32x4 = 512
        int kk = c4 >> 3, k8 = (c4 & 7) * 4;
        int* dst = (int*)&stateL[kk * 640 + row * 40 + k8];
        if (row < ACT) {
            f32x4 x = *(const f32x4*)(state + ((size_t)b * ACT + row) * CC + c4 * 4);
            dst[0] = pk_bf16(x[0], x[1]); dst[1] = pk_bf16(x[2], x[3]);
        } else { dst[0] = 0; dst[1] = 0; }
    }
    if (t < 256) { b2L[t] = lin2_b[t]; muL[t] = mu_w[t]; sgL[t] = sig_w[t]; }
    if (t >= 256 && t < 384) {                // ssum: fused GCN aggregate
        int c = t - 256;
        const float* sp = state + (size_t)b * ACT * CC + c;
        float s = 0.f;
        #pragma unroll
        for (int r = 0; r < ACT; ++r) s += sp[r * CC];
        ssumL[c] = s * (1.f / 14.f);
    }
    if (t < 192) { mu_acc[t] = 0.f; sg_acc[t] = 0.f; }
    if (t == 0) lp_acc = 0.f;
    __syncthreads();

    // ---- phase A2: g then w (small dots, VALU) ----
    if (t < 128) {
        float a = 0.f;
        #pragma unroll 8
        for (int k = 0; k < 128; ++k) a += b2f(cwTbf[k * 128 + t]) * ssumL[k];
        gL[t] = fmaxf(a + conv_b[t], 0.f);
    }
    __syncthreads();
    if (t < 256) {
        float a = 0.f;
        #pragma unroll 8
        for (int k = 0; k < 128; ++k) a += b2f(w1sTbf[k * 256 + t]) * gL[k];
        wL[t] = a + lin1_b[t];
    }
    __syncthreads();

    // ---- phase B: node GEMM (u = W1L@x + w | v = W1R@x) ----
    f32x4 zero4 = {0.f, 0.f, 0.f, 0.f};
    f32x4 nacc[4];
    nacc[0] = zero4; nacc[1] = zero4; nacc[2] = zero4; nacc[3] = zero4;
    #pragma unroll
    for (int c = 0; c < 4; ++c) {
        s16x8 a8 = *(const s16x8*)&stateL[c * 640 + ln * 40 + q * 8];
        #pragma unroll
        for (int i = 0; i < 4; ++i) {
            int ct = w + 8 * i;               // 0..31
            s16x8 b8 = *(const s16x8*)&W1bf[(size_t)(ct * 16 + ln) * CC + c * 32 + q * 8];
            nacc[i] = __builtin_amdgcn_mfma_f32_16x16x32_bf16(a8, b8, nacc[i], 0, 0, 0);
        }
    }
    #pragma unroll
    for (int i = 0; i < 4; ++i) {
        int col = (w + 8 * i) * 16 + ln;
        float wadd = (col < HH) ? wL[col] : 0.f;
        #pragma unroll
        for (int rg = 0; rg < 4; ++rg) {
            int node = q * 4 + rg;
            if (node < ACT) nodeL[node * NS + col] = f2bf(nacc[i][rg] + wadd);
        }
    }

    // ---- W2 strip (32 rows x K=256) into VGPRs ----
    s16x8 wa[16];
    #pragma unroll
    for (int c = 0; c < 16; ++c)
        wa[c] = *(const s16x8*)&W2bf[(size_t)(w * 32 + l32) * HH + c * 16 + hf * 8];
    __syncthreads();   // nodeL visible

    // cooperative H1 build: 512 threads x 2 slots; each element computed once
    auto build = [&](int tile, int bufi) {
        int e32 = t & 31;
        int e = tile * 32 + e32;
        bool ok = e < EPB;
        int uo = 0, vo = 0;
        if (ok) { int2 p = ((const int2*)edges)[e]; uo = p.x * NS; vo = p.y * NS + HH; }
        int sl = t >> 5;                       // 0..15
        #pragma unroll
        for (int s = 0; s < 2; ++s) {
            int slot = sl + 16 * s;            // 0..31
            int chunk = slot >> 1, half = slot & 1;
            int koff = chunk * 16 + half * 8;
            int o[4] = {0, 0, 0, 0};
            if (ok) {
                s16x8 u8 = *(const s16x8*)&nodeL[uo + koff];
                s16x8 v8 = *(const s16x8*)&nodeL[vo + koff];
                const int* ui = (const int*)&u8;
                const int* vi = (const int*)&v8;
                #pragma unroll
                for (int j = 0; j < 4; ++j) {
                    int uu = ui[j], vv = vi[j];
                    float s0 = bflo(uu) + bflo(vv);
                    float s1 = bfhi(uu) + bfhi(vv);
                    o[j] = pk_bf16(leaky(s0), leaky(s1));
                }
            }
            *(s16x8*)&h1L[bufi][chunk * 512 + (half * 32 + e32) * 8] = *(const s16x8*)o;
        }
    };

    build(0, 0);
    for (int tile = 0; tile < 6; ++tile) {
        __syncthreads();
        if (tile < 5) build(tile + 1, (tile + 1) & 1);
        const int buf = tile & 1;
        f32x16 acc;
        #pragma unroll
        for (int r = 0; r < 16; ++r) acc[r] = 0.f;
        #pragma unroll
        for (int c = 0; c < 16; ++c) {
            s16x8 b8 = *(const s16x8*)&h1L[buf][c * 512 + lane * 8];
            acc = __builtin_amdgcn_mfma_f32_32x32x16_bf16(wa[c], b8, acc, 0, 0, 0);
        }
        // in-lane epilogue: lane&31 = edge; regs = 32 n-rows of this strip
        float pmu = 0.f, psg = 0.f;
        const int ns = w * 32;
        #pragma unroll
        for (int r = 0; r < 16; ++r) {
            int n = ns + (r & 3) + 8 * (r >> 2) + 4 * hf;
            float h2 = leaky(acc[r] + b2L[n]);     // LDS broadcast reads
            pmu += muL[n] * h2;
            psg += sgL[n] * h2;
        }
        pmu += __shfl_xor(pmu, 32);
        psg += __shfl_xor(psg, 32);
        if (l32 == lane) {                          // lanes 0..31
            atomicAdd(&mu_acc[tile * 32 + l32], pmu);
            atomicAdd(&sg_acc[tile * 32 + l32], psg);
        }
    }
    __syncthreads();

    // ---- final head ----
    float lpv = 0.f;
    if (t < EPB) {
        float mu = softplusf(mu_acc[t] + mu_b[0]);
        float sd = softplusf(sg_acc[t] + sig_b[0]);
        float z = noise[(size_t)b * EPB + t];
        out[(size_t)b * EPB + t] = mu + sd * z;
        lpv = -0.5f * z * z - logf(sd);
    }
    if (w < 3) {                                    // waves covering t<192
        #pragma unroll
        for (int off = 1; off < 64; off <<= 1) lpv += __shfl_xor(lpv, off);
        if (lane == 0) atomicAdd(&lp_acc, lpv);
    }
    __syncthreads();
    if (t == 0) out[M2 + b] = lp_acc + LP_CONST;
}

// ---------------------------------------------------------------------------
extern "C" void kernel_launch(void* const* d_in, const int* in_sizes, int n_in,
                              void* d_out, int out_size, void* d_ws, size_t ws_size,
                              hipStream_t stream)
{
    const float* state  = (const float*)d_in[0];
    const float* conv_w = (const float*)d_in[1];
    const float* conv_b = (const float*)d_in[2];
    const float* lin1_w = (const float*)d_in[3];
    const float* lin1_b = (const float*)d_in[4];
    const float* lin2_w = (const float*)d_in[5];
    const float* lin2_b = (const float*)d_in[6];
    const float* mu_w   = (const float*)d_in[7];
    const float* mu_b   = (const float*)d_in[8];
    const float* sig_w  = (const float*)d_in[9];
    const float* sig_b  = (const float*)d_in[10];
    const float* noise  = (const float*)d_in[11];
    const int*   edges  = (const int*)d_in[13];
    float* out = (float*)d_out;

    char* ws = (char*)d_ws;
    short* W2bf   = (short*)ws;  ws += 65536 * 2;
    short* W1bf   = (short*)ws;  ws += 65536 * 2;
    short* cwTbf  = (short*)ws;  ws += 16384 * 2;
    short* w1sTbf = (short*)ws;  ws += 32768 * 2;

    prep_kernel<<<256, 256, 0, stream>>>(conv_w, lin1_w, lin2_w,
                                         W2bf, W1bf, cwTbf, w1sTbf);
    actor_kernel<<<NB, 512, 0, stream>>>(state, W1bf, W2bf,
                                         cwTbf, conv_b, w1sTbf, lin1_b,
                                         lin2_b, mu_w, mu_b, sig_w, sig_b,
                                         noise, edges, out);
}

// Round 8
// 211.645 us; speedup vs baseline: 1.5820x; 1.1209x over previous
//
#include <hip/hip_runtime.h>
#include <hip/hip_bf16.h>

#define ACT 14
#define CC 128
#define HH 256
#define EPB 182                 // edges per batch (14*13)
#define NB 2048
#define M2 (NB*EPB)             // 372736 edge-rows
#define NS 520                  // nodeL stride in shorts
#define LP_CONST (-182.0f * 0.91893853320467274f)   // -E*0.5*ln(2pi)

typedef short s16x8 __attribute__((ext_vector_type(8)));
typedef float f32x4 __attribute__((ext_vector_type(4)));
typedef float f32x16 __attribute__((ext_vector_type(16)));

__device__ __forceinline__ short f2bf(float f) {
    unsigned u = __float_as_uint(f);
    unsigned r = (u + 0x7fffu + ((u >> 16) & 1u)) >> 16;   // RNE
    return (short)r;
}
__device__ __forceinline__ float b2f(short s) {
    return __uint_as_float(((unsigned)(unsigned short)s) << 16);
}
__device__ __forceinline__ float bflo(int m) { return __uint_as_float(((unsigned)m) << 16); }
__device__ __forceinline__ float bfhi(int m) { return __uint_as_float((unsigned)m & 0xffff0000u); }
__device__ __forceinline__ float leaky(float x) { return fmaxf(x, 0.01f * x); }
__device__ __forceinline__ float softplusf(float x) { return x > 15.f ? x : log1pf(expf(x)); }

union bf2u { __hip_bfloat162 h; int i; };
__device__ __forceinline__ int pk_bf16(float a, float b) {
    bf2u u; u.h = __float22bfloat162_rn(make_float2(a, b));
    return u.i;
}

// ---------------------------------------------------------------------------
// prep: one-time weight conversions (256 blocks x 256)
// ---------------------------------------------------------------------------
__global__ __launch_bounds__(256) void prep_kernel(
    const float* __restrict__ conv_w, const float* __restrict__ lin1_w,
    const float* __restrict__ lin2_w,
    short* __restrict__ W2bf, short* __restrict__ W1bf,
    short* __restrict__ cwTbf, short* __restrict__ w1sTbf)
{
    int i = blockIdx.x * 256 + threadIdx.x;
    W2bf[i] = f2bf(lin2_w[i]);
    {
        int n = i >> 7, k = i & 127;
        float v = (n < 256) ? lin1_w[n * 256 + k] : lin1_w[(n - 256) * 256 + 128 + k];
        W1bf[i] = f2bf(v);
    }
    if (i < 16384) {
        int k = i >> 7, j = i & 127;
        cwTbf[i] = f2bf(conv_w[j * 128 + k]);
    }
    if (i < 32768) {
        int k = i >> 8, h = i & 255;
        w1sTbf[i] = f2bf(lin1_w[h * 256 + k] + lin1_w[h * 256 + 128 + k]);
    }
}

// ---------------------------------------------------------------------------
// actor: TWO batches per block (1024 blocks), 512 threads = 8 waves.
//  A : stage state bf16 (both batches, aliased into h1L); ssum; tables.
//  A2: g (2-way k-split over all 512 thr) then w (1 output/thread).
//  B : node GEMM -> nodeL[2] (u+w | v), 16x16x32 MFMA.
//  C : 12 edge-tiles of 32 (6 per batch); cooperative H1 build into
//      frag-order double-buffered LDS; W2 32-row strip per wave in VGPRs;
//      32x32x16 MFMA; in-lane mu/sig epilogue.
// ---------------------------------------------------------------------------
__global__ __launch_bounds__(512, 4) void actor_kernel(
    const float* __restrict__ state, const short* __restrict__ W1bf,
    const short* __restrict__ W2bf,
    const short* __restrict__ cwTbf, const float* __restrict__ conv_b,
    const short* __restrict__ w1sTbf, const float* __restrict__ lin1_b,
    const float* __restrict__ lin2_b, const float* __restrict__ mu_w,
    const float* __restrict__ mu_b, const float* __restrict__ sig_w,
    const float* __restrict__ sig_b, const float* __restrict__ noise,
    const int* __restrict__ edges, float* __restrict__ out)
{
    __shared__ short h1L[2][8192];           // 32 KB; [0] front aliased below
    __shared__ short nodeL[2 * ACT * NS];    // 29120 B
    __shared__ float ssumL[2][128];
    __shared__ float gL[2][128];
    __shared__ float wL[2][256];
    __shared__ float b2L[256], muL[256], sgL[256];
    __shared__ float mu_acc[384], sg_acc[384];
    __shared__ float lp_acc[2];

    short* stateL = &h1L[0][0];              // 2*2560 shorts = 10240 B (dead before build)
    float* pp     = (float*)&h1L[0][5120];   // 512 f32 partials (dead before build)

    const int t = threadIdx.x, b = blockIdx.x;
    const int lane = t & 63, ln = lane & 15, q = lane >> 4;
    const int w = t >> 6;                     // wave 0..7
    const int l32 = lane & 31, hf = lane >> 5;

    // ---- phase A ----
    #pragma unroll
    for (int it = 0; it < 2; ++it) {
        int idx = it * 512 + t;
        int bt = idx >> 9, row = (idx >> 5) & 15, c4 = idx & 31;
        int kk = c4 >> 3, k8 = (c4 & 7) * 4;
        int* dst = (int*)&stateL[bt * 2560 + kk * 640 + row * 40 + k8];
        if (row < ACT) {
            f32x4 x = *(const f32x4*)(state + ((size_t)(2 * b + bt) * ACT + row) * CC + c4 * 4);
            dst[0] = pk_bf16(x[0], x[1]); dst[1] = pk_bf16(x[2], x[3]);
        } else { dst[0] = 0; dst[1] = 0; }
    }
    if (t < 256) { b2L[t] = lin2_b[t]; muL[t] = mu_w[t]; sgL[t] = sig_w[t]; }
    else {
        int i = t - 256, bt = i >> 7, c = i & 127;    // ssum, both batches
        const float* sp = state + (size_t)(2 * b + bt) * ACT * CC + c;
        float s = 0.f;
        #pragma unroll
        for (int r = 0; r < ACT; ++r) s += sp[r * CC];
        ssumL[bt][c] = s * (1.f / 14.f);
    }
    if (t < 384) { mu_acc[t] = 0.f; sg_acc[t] = 0.f; }
    if (t < 2) lp_acc[t] = 0.f;
    __syncthreads();

    // ---- phase A2: g (2-way k-split, all threads) ----
    {
        int bt = t >> 8, s = (t >> 7) & 1, j = t & 127;
        const float* ss = ssumL[bt];
        float a = 0.f;
        #pragma unroll 8
        for (int kk = 0; kk < 64; ++kk) {
            int k = s * 64 + kk;
            a += b2f(cwTbf[k * 128 + j]) * ss[k];
        }
        pp[t] = a;
    }
    __syncthreads();
    if (t < 256) {
        int bt = t >> 7, j = t & 127;
        float a = pp[bt * 256 + j] + pp[bt * 256 + 128 + j] + conv_b[j];
        gL[bt][j] = fmaxf(a, 0.f);
    }
    __syncthreads();
    // ---- w: one output per thread ----
    {
        int bt = t >> 8, h = t & 255;
        const float* gg = gL[bt];
        float a = 0.f;
        #pragma unroll 8
        for (int k = 0; k < 128; ++k)
            a += b2f(w1sTbf[k * 256 + h]) * gg[k];
        wL[bt][h] = a + lin1_b[h];
    }
    __syncthreads();

    // ---- phase B: node GEMM (u = W1L@x + w | v = W1R@x), both batches ----
    f32x4 zero4 = {0.f, 0.f, 0.f, 0.f};
    f32x4 nacc[2][4];
    #pragma unroll
    for (int bt = 0; bt < 2; ++bt) {
        nacc[bt][0] = zero4; nacc[bt][1] = zero4;
        nacc[bt][2] = zero4; nacc[bt][3] = zero4;
    }
    #pragma unroll
    for (int c = 0; c < 4; ++c) {
        s16x8 a80 = *(const s16x8*)&stateL[0 * 2560 + c * 640 + ln * 40 + q * 8];
        s16x8 a81 = *(const s16x8*)&stateL[1 * 2560 + c * 640 + ln * 40 + q * 8];
        #pragma unroll
        for (int i = 0; i < 4; ++i) {
            int ct = w + 8 * i;               // 0..31
            s16x8 b8 = *(const s16x8*)&W1bf[(size_t)(ct * 16 + ln) * CC + c * 32 + q * 8];
            nacc[0][i] = __builtin_amdgcn_mfma_f32_16x16x32_bf16(a80, b8, nacc[0][i], 0, 0, 0);
            nacc[1][i] = __builtin_amdgcn_mfma_f32_16x16x32_bf16(a81, b8, nacc[1][i], 0, 0, 0);
        }
    }
    #pragma unroll
    for (int bt = 0; bt < 2; ++bt)
        #pragma unroll
        for (int i = 0; i < 4; ++i) {
            int col = (w + 8 * i) * 16 + ln;
            float wadd = (col < HH) ? wL[bt][col] : 0.f;
            #pragma unroll
            for (int rg = 0; rg < 4; ++rg) {
                int node = q * 4 + rg;
                if (node < ACT) nodeL[(bt * ACT + node) * NS + col] = f2bf(nacc[bt][i][rg] + wadd);
            }
        }

    // ---- W2 strip (32 rows x K=256) into VGPRs ----
    s16x8 wa[16];
    #pragma unroll
    for (int c = 0; c < 16; ++c)
        wa[c] = *(const s16x8*)&W2bf[(size_t)(w * 32 + l32) * HH + c * 16 + hf * 8];
    __syncthreads();   // nodeL visible; stateL/pp now dead

    // cooperative H1 build (each element computed once), frag-order layout
    auto build = [&](int tile, int bufi) {
        int bt = (tile >= 6) ? 1 : 0;
        int e32 = t & 31;
        int e = (tile - bt * 6) * 32 + e32;
        bool ok = e < EPB;
        int base = bt * ACT * NS;
        int uo = base, vo = base + HH;
        if (ok) { int2 p = ((const int2*)edges)[e]; uo += p.x * NS; vo += p.y * NS; }
        int sl = t >> 5;                       // 0..15
        #pragma unroll
        for (int s = 0; s < 2; ++s) {
            int slot = sl + 16 * s;            // 0..31
            int chunk = slot >> 1, half = slot & 1;
            int koff = chunk * 16 + half * 8;
            int o[4] = {0, 0, 0, 0};
            if (ok) {
                s16x8 u8 = *(const s16x8*)&nodeL[uo + koff];
                s16x8 v8 = *(const s16x8*)&nodeL[vo + koff];
                const int* ui = (const int*)&u8;
                const int* vi = (const int*)&v8;
                #pragma unroll
                for (int j = 0; j < 4; ++j) {
                    int uu = ui[j], vv = vi[j];
                    float s0 = bflo(uu) + bflo(vv);
                    float s1 = bfhi(uu) + bfhi(vv);
                    o[j] = pk_bf16(leaky(s0), leaky(s1));
                }
            }
            *(s16x8*)&h1L[bufi][chunk * 512 + (half * 32 + e32) * 8] = *(const s16x8*)o;
        }
    };

    build(0, 0);
    for (int tile = 0; tile < 12; ++tile) {
        __syncthreads();
        if (tile < 11) build(tile + 1, (tile + 1) & 1);
        const int buf = tile & 1;
        f32x16 acc;
        #pragma unroll
        for (int r = 0; r < 16; ++r) acc[r] = 0.f;
        #pragma unroll
        for (int c = 0; c < 16; ++c) {
            s16x8 b8 = *(const s16x8*)&h1L[buf][c * 512 + lane * 8];
            acc = __builtin_amdgcn_mfma_f32_32x32x16_bf16(wa[c], b8, acc, 0, 0, 0);
        }
        // in-lane epilogue: lane&31 = edge; regs = 32 n-rows of this strip
        int bt = (tile >= 6) ? 1 : 0;
        int col0 = (tile - bt * 6) * 32;
        float pmu = 0.f, psg = 0.f;
        const int nsb = w * 32;
        #pragma unroll
        for (int r = 0; r < 16; ++r) {
            int n = nsb + (r & 3) + 8 * (r >> 2) + 4 * hf;
            float h2 = leaky(acc[r] + b2L[n]);
            pmu += muL[n] * h2;
            psg += sgL[n] * h2;
        }
        pmu += __shfl_xor(pmu, 32);
        psg += __shfl_xor(psg, 32);
        if (lane < 32) {
            atomicAdd(&mu_acc[bt * 192 + col0 + l32], pmu);
            atomicAdd(&sg_acc[bt * 192 + col0 + l32], psg);
        }
    }
    __syncthreads();

    // ---- final head, both batches ----
    float lpv = 0.f;
    {
        int bt = t >> 8, i = t & 255;
        if (i < EPB) {
            float mu = softplusf(mu_acc[bt * 192 + i] + mu_b[0]);
            float sd = softplusf(sg_acc[bt * 192 + i] + sig_b[0]);
            float z = noise[(size_t)(2 * b + bt) * EPB + i];
            out[(size_t)(2 * b + bt) * EPB + i] = mu + sd * z;
            lpv = -0.5f * z * z - logf(sd);
        }
    }
    #pragma unroll
    for (int off = 1; off < 64; off <<= 1) lpv += __shfl_xor(lpv, off);
    if (lane == 0) atomicAdd(&lp_acc[t >> 8], lpv);
    __syncthreads();
    if (t < 2) out[M2 + 2 * b + t] = lp_acc[t] + LP_CONST;
}

// ---------------------------------------------------------------------------
extern "C" void kernel_launch(void* const* d_in, const int* in_sizes, int n_in,
                              void* d_out, int out_size, void* d_ws, size_t ws_size,
                              hipStream_t stream)
{
    const float* state  = (const float*)d_in[0];
    const float* conv_w = (const float*)d_in[1];
    const float* conv_b = (const float*)d_in[2];
    const float* lin1_w = (const float*)d_in[3];
    const float* lin1_b = (const float*)d_in[4];
    const float* lin2_w = (const float*)d_in[5];
    const float* lin2_b = (const float*)d_in[6];
    const float* mu_w   = (const float*)d_in[7];
    const float* mu_b   = (const float*)d_in[8];
    const float* sig_w  = (const float*)d_in[9];
    const float* sig_b  = (const float*)d_in[10];
    const float* noise  = (const float*)d_in[11];
    const int*   edges  = (const int*)d_in[13];
    float* out = (float*)d_out;

    char* ws = (char*)d_ws;
    short* W2bf   = (short*)ws;  ws += 65536 * 2;
    short* W1bf   = (short*)ws;  ws += 65536 * 2;
    short* cwTbf  = (short*)ws;  ws += 16384 * 2;
    short* w1sTbf = (short*)ws;  ws += 32768 * 2;

    prep_kernel<<<256, 256, 0, stream>>>(conv_w, lin1_w, lin2_w,
                                         W2bf, W1bf, cwTbf, w1sTbf);
    actor_kernel<<<NB / 2, 512, 0, stream>>>(state, W1bf, W2bf,
                                             cwTbf, conv_b, w1sTbf, lin1_b,
                                             lin2_b, mu_w, mu_b, sig_w, sig_b,
                                             noise, edges, out);
}